// Round 7
// baseline (360.691 us; speedup 1.0000x reference)
//
#include <hip/hip_runtime.h>

typedef __attribute__((ext_vector_type(8))) short short8;
typedef __attribute__((ext_vector_type(4))) float f32x4;

constexpr float BN_EPS = 1e-5f;
#define NBUCKETS 128  // buckets of 1024 nodes; N <= 131072

__device__ __forceinline__ ushort f2bf(float f) {
  uint u = __float_as_uint(f);
  u = (u + 0x7fffu + ((u >> 16) & 1u)) >> 16;
  return (ushort)u;
}
__device__ __forceinline__ float bf2f(ushort h) { return __uint_as_float((uint)h << 16); }
__device__ __forceinline__ float bf2f_lo(uint v) { return __uint_as_float(v << 16); }
__device__ __forceinline__ float bf2f_hi(uint v) { return __uint_as_float(v & 0xffff0000u); }

typedef __attribute__((address_space(1))) const unsigned int* as1_cu32;
typedef __attribute__((address_space(3))) unsigned int* as3_u32;
__device__ __forceinline__ void gload_lds16(const void* g, void* l) {
  __builtin_amdgcn_global_load_lds((as1_cu32)g, (as3_u32)l, 16, 0, 0);
}

// ---------------- fp32 -> bf16 cast (x) ----------------

__global__ __launch_bounds__(256) void k_cast(const float* __restrict__ in, ushort* __restrict__ out, int n4) {
  for (int i = blockIdx.x * 256 + threadIdx.x; i < n4; i += gridDim.x * 256) {
    float4 v = reinterpret_cast<const float4*>(in)[i];
    ushort4 o;
    o.x = f2bf(v.x); o.y = f2bf(v.y); o.z = f2bf(v.z); o.w = f2bf(v.w);
    reinterpret_cast<ushort4*>(out)[i] = o;
  }
}

// all weight preps in one launch: blocks 0-63 cast the 4 128x128 weights,
// blocks 64-127 build the packed layer-2 weight (rows 0..C-1=Wl2, 64..64+C-1=Wr2, rest 0)
__global__ __launch_bounds__(256) void k_prep_weights(const float* __restrict__ Wl0, const float* __restrict__ Wr0,
                                                      const float* __restrict__ Wl1, const float* __restrict__ Wr1,
                                                      const float* __restrict__ Wl2, const float* __restrict__ Wr2,
                                                      ushort* __restrict__ W0l, ushort* __restrict__ W0r,
                                                      ushort* __restrict__ W1l, ushort* __restrict__ W1r,
                                                      ushort* __restrict__ Wc, int C) {
  int b = blockIdx.x;
  if (b < 64) {
    const float* src = (b < 16) ? Wl0 : (b < 32) ? Wr0 : (b < 48) ? Wl1 : Wr1;
    ushort* dst = (b < 16) ? W0l : (b < 32) ? W0r : (b < 48) ? W1l : W1r;
    int i = (b & 15) * 256 + threadIdx.x;  // 4096 float4 per matrix
    float4 v = reinterpret_cast<const float4*>(src)[i];
    ushort4 o;
    o.x = f2bf(v.x); o.y = f2bf(v.y); o.z = f2bf(v.z); o.w = f2bf(v.w);
    reinterpret_cast<ushort4*>(dst)[i] = o;
  } else {
    int i = (b - 64) * 256 + threadIdx.x;  // 16384
    int r = i >> 7, k = i & 127;
    float v = 0.f;
    if (r < C) v = Wl2[r * 128 + k];
    else if (r >= 64 && r < 64 + C) v = Wr2[(r - 64) * 128 + k];
    Wc[i] = f2bf(v);
  }
}

// ---------------- bucketed CSR build ----------------

__global__ __launch_bounds__(256) void k_bucket_hist(const int* __restrict__ dst, int E, int* __restrict__ bcnt) {
  __shared__ int h[NBUCKETS];
  for (int i = threadIdx.x; i < NBUCKETS; i += 256) h[i] = 0;
  __syncthreads();
  for (int i = blockIdx.x * 256 + threadIdx.x; i < E; i += gridDim.x * 256)
    atomicAdd(&h[dst[i] >> 10], 1);
  __syncthreads();
  for (int i = threadIdx.x; i < NBUCKETS; i += 256)
    if (h[i]) atomicAdd(&bcnt[i], h[i]);
}

__global__ __launch_bounds__(128) void k_bucket_scan(const int* __restrict__ bcnt, int* __restrict__ brp,
                                                     int* __restrict__ bcur) {
  __shared__ int sh[NBUCKETS];
  int tid = threadIdx.x;
  int v = bcnt[tid];
  sh[tid] = v;
  __syncthreads();
  for (int off = 1; off < NBUCKETS; off <<= 1) {
    int t = (tid >= off) ? sh[tid - off] : 0;
    __syncthreads();
    sh[tid] += t;
    __syncthreads();
  }
  int ex = sh[tid] - v;
  brp[tid] = ex;
  bcur[tid] = ex;
  if (tid == NBUCKETS - 1) brp[NBUCKETS] = sh[tid];
}

// bin edges into bucket-segmented packed array: (dst & 1023) | (src << 10)
__global__ __launch_bounds__(256) void k_binscatter(const int* __restrict__ dst, const int* __restrict__ src, int E,
                                                    int* __restrict__ bcur, uint* __restrict__ ebuf) {
  __shared__ int h[NBUCKETS];
  __shared__ int base[NBUCKETS];
  __shared__ int cur[NBUCKETS];
  const int e0 = blockIdx.x * 8192;
  const int e1 = min(e0 + 8192, E);
  for (int i = threadIdx.x; i < NBUCKETS; i += 256) h[i] = 0;
  __syncthreads();
  for (int e = e0 + threadIdx.x; e < e1; e += 256) atomicAdd(&h[dst[e] >> 10], 1);
  __syncthreads();
  if (threadIdx.x < NBUCKETS) {
    base[threadIdx.x] = atomicAdd(&bcur[threadIdx.x], h[threadIdx.x]);
    cur[threadIdx.x] = 0;
  }
  __syncthreads();
  for (int e = e0 + threadIdx.x; e < e1; e += 256) {
    int d = dst[e];
    int b = d >> 10;
    int pos = base[b] + atomicAdd(&cur[b], 1);
    ebuf[pos] = (uint)(d & 1023) | ((uint)src[e] << 10);
  }
}

// per-bucket: node counts, LDS scan, rp/deg_inv, scatter src into csr (all atomics in LDS)
// also accumulates the global degree histogram for the degree-sorted permutation
__global__ __launch_bounds__(512) void k_bucket_build(const uint* __restrict__ ebuf, const int* __restrict__ brp,
                                                      int* __restrict__ rp, float* __restrict__ deg_inv,
                                                      int* __restrict__ csr, int* __restrict__ dhist,
                                                      int N, int E) {
  __shared__ int cnt[1024];
  __shared__ int pre[1024];
  __shared__ int tmp[1024];
  __shared__ int dh[64];
  const int blk = blockIdx.x, tid = threadIdx.x;
  const int base = blk << 10;
  const int p0 = brp[blk], p1 = brp[blk + 1];
  for (int i = tid; i < 1024; i += 512) cnt[i] = 0;
  if (tid < 64) dh[tid] = 0;
  __syncthreads();
  for (int p = p0 + tid; p < p1; p += 512) atomicAdd(&cnt[ebuf[p] & 1023u], 1);
  __syncthreads();
  for (int i = tid; i < 1024; i += 512) pre[i] = cnt[i];
  __syncthreads();
  for (int off = 1; off < 1024; off <<= 1) {
    for (int i = tid; i < 1024; i += 512) tmp[i] = (i >= off) ? pre[i - off] : 0;
    __syncthreads();
    for (int i = tid; i < 1024; i += 512) pre[i] += tmp[i];
    __syncthreads();
  }
  for (int i = tid; i < 1024; i += 512) {
    int node = base + i;
    if (node < N) {
      int ex = pre[i] - cnt[i];
      rp[node] = p0 + ex;
      deg_inv[node] = 1.0f / (float)max(cnt[i], 1);
      atomicAdd(&dh[min(cnt[i], 63)], 1);
    }
    tmp[i] = pre[i] - cnt[i];  // scatter cursor
  }
  if (tid == 0 && blk == gridDim.x - 1) rp[N] = E;
  __syncthreads();
  for (int p = p0 + tid; p < p1; p += 512) {
    uint pr = ebuf[p];
    int pos = p0 + atomicAdd(&tmp[pr & 1023u], 1);
    csr[pos] = (int)(pr >> 10);
  }
  if (tid < 64 && dh[tid]) atomicAdd(&dhist[tid], dh[tid]);
}

// ---------------- degree-sorted permutation (counting sort, 64 bins) ----------------

__global__ __launch_bounds__(64) void k_deg_scan(const int* __restrict__ dhist, int* __restrict__ dcur) {
  __shared__ int sh[64];
  int t = threadIdx.x;
  int v = dhist[t];
  sh[t] = v;
  __syncthreads();
  for (int off = 1; off < 64; off <<= 1) {
    int u = (t >= off) ? sh[t - off] : 0;
    __syncthreads();
    sh[t] += u;
    __syncthreads();
  }
  dcur[t] = sh[t] - v;  // exclusive
}

__global__ __launch_bounds__(512) void k_deg_scatter(const int* __restrict__ rp, int N,
                                                     int* __restrict__ dcur, int* __restrict__ perm) {
  __shared__ int h[64], base[64], cur[64];
  const int n0 = blockIdx.x * 8192;
  const int n1 = min(n0 + 8192, N);
  if (threadIdx.x < 64) h[threadIdx.x] = 0;
  __syncthreads();
  for (int i = n0 + threadIdx.x; i < n1; i += 512)
    atomicAdd(&h[min(rp[i + 1] - rp[i], 63)], 1);
  __syncthreads();
  if (threadIdx.x < 64) {
    base[threadIdx.x] = atomicAdd(&dcur[threadIdx.x], h[threadIdx.x]);
    cur[threadIdx.x] = 0;
  }
  __syncthreads();
  for (int i = n0 + threadIdx.x; i < n1; i += 512) {
    int d = min(rp[i + 1] - rp[i], 63);
    perm[base[d] + atomicAdd(&cur[d], 1)] = i;
  }
}

// ---------------- aggregation (bf16 rows; 4 nodes/wave, degree-sorted) ----------------

__global__ __launch_bounds__(256) void k_agg128(const ushort* __restrict__ X, const int* __restrict__ rp,
                                                const int* __restrict__ csr, const float* __restrict__ deg_inv,
                                                const int* __restrict__ perm,
                                                ushort* __restrict__ out, int N) {
  const int wave = threadIdx.x >> 6, lane = threadIdx.x & 63;
  const int sub = lane >> 4, li = lane & 15;
  const int gi = blockIdx.x * 16 + wave * 4 + sub;
  if (gi >= N) return;
  const int node = perm[gi];
  const int start = rp[node];
  const int c = rp[node + 1] - start;
  const uint4* X16 = reinterpret_cast<const uint4*>(X);
  float a0 = 0.f, a1 = 0.f, a2 = 0.f, a3 = 0.f, a4 = 0.f, a5 = 0.f, a6 = 0.f, a7 = 0.f;
  int p = 0;
  for (; p + 7 < c; p += 8) {
    int idx[8];
#pragma unroll
    for (int u = 0; u < 8; ++u) idx[u] = csr[start + p + u];
    uint4 v[8];
#pragma unroll
    for (int u = 0; u < 8; ++u) v[u] = X16[(size_t)idx[u] * 16 + li];
#pragma unroll
    for (int u = 0; u < 8; ++u) {
      a0 += bf2f_lo(v[u].x); a1 += bf2f_hi(v[u].x);
      a2 += bf2f_lo(v[u].y); a3 += bf2f_hi(v[u].y);
      a4 += bf2f_lo(v[u].z); a5 += bf2f_hi(v[u].z);
      a6 += bf2f_lo(v[u].w); a7 += bf2f_hi(v[u].w);
    }
  }
  if (p + 3 < c) {
    int idx[4];
#pragma unroll
    for (int u = 0; u < 4; ++u) idx[u] = csr[start + p + u];
    uint4 v[4];
#pragma unroll
    for (int u = 0; u < 4; ++u) v[u] = X16[(size_t)idx[u] * 16 + li];
#pragma unroll
    for (int u = 0; u < 4; ++u) {
      a0 += bf2f_lo(v[u].x); a1 += bf2f_hi(v[u].x);
      a2 += bf2f_lo(v[u].y); a3 += bf2f_hi(v[u].y);
      a4 += bf2f_lo(v[u].z); a5 += bf2f_hi(v[u].z);
      a6 += bf2f_lo(v[u].w); a7 += bf2f_hi(v[u].w);
    }
    p += 4;
  }
  for (; p < c; ++p) {
    uint4 v = X16[(size_t)csr[start + p] * 16 + li];
    a0 += bf2f_lo(v.x); a1 += bf2f_hi(v.x);
    a2 += bf2f_lo(v.y); a3 += bf2f_hi(v.y);
    a4 += bf2f_lo(v.z); a5 += bf2f_hi(v.z);
    a6 += bf2f_lo(v.w); a7 += bf2f_hi(v.w);
  }
  const float di = deg_inv[node];
  uint4 o;
  o.x = (uint)f2bf(a0 * di) | ((uint)f2bf(a1 * di) << 16);
  o.y = (uint)f2bf(a2 * di) | ((uint)f2bf(a3 * di) << 16);
  o.z = (uint)f2bf(a4 * di) | ((uint)f2bf(a5 * di) << 16);
  o.w = (uint)f2bf(a6 * di) | ((uint)f2bf(a7 * di) << 16);
  reinterpret_cast<uint4*>(out)[(size_t)node * 16 + li] = o;
}

// ---------------- MFMA GEMM v3: wave-owned column tiles ----------------
// 512 threads = 8 waves; wave w owns output cols [16w,16w+16). Weights for the
// strip live in registers. A/B staged via global_load_lds with pre-swizzled
// source. DUAL: Z = A@WA^T + B@WB^T + BN partials, stores [N][128] rows.
// SINGLE: Z = A@WA^T, splits output rows into Yb[N][64] (cols 0..63) and
// Rb[N][64] (cols 64..127) for a dense layer-2 gather.

template <bool DUAL>
__global__ __launch_bounds__(512, 6) void k_gemm(const ushort* __restrict__ A, const ushort* __restrict__ B,
                                                 const ushort* __restrict__ WA, const ushort* __restrict__ WB,
                                                 float* __restrict__ partial, ushort* __restrict__ Z,
                                                 ushort* __restrict__ Z2, int M) {
  __shared__ ushort sA[64 * 128];
  __shared__ ushort sB[DUAL ? 64 * 128 : 64];
  __shared__ ushort sZ[64 * 128];
  const int tid = threadIdx.x;
  const int wave = tid >> 6, lane = tid & 63;
  const int rfrag = lane & 15, kgrp = lane >> 4;
  const int row0 = blockIdx.x * 64;

  // stage: wave w fills chunks {2w, 2w+1}; chunk = 1KB = 4 rows; source pre-swizzled
#pragma unroll
  for (int i = 0; i < 2; ++i) {
    int c = wave * 2 + i;
    int lb = c * 1024 + lane * 16;
    int row = lb >> 8, bin = lb & 255;
    int gr = min(row0 + row, M - 1);
    int sb = bin ^ ((row & 7) << 4);
    gload_lds16((const char*)A + (size_t)gr * 256 + sb, (char*)sA + c * 1024);
    if (DUAL) gload_lds16((const char*)B + (size_t)gr * 256 + sb, (char*)sB + c * 1024);
  }

  // weight fragments for this wave's column strip -> registers
  short8 wfA[4], wfB[4];
  {
    const ushort* wa = WA + (wave * 16 + rfrag) * 128 + kgrp * 8;
#pragma unroll
    for (int s = 0; s < 4; ++s) wfA[s] = *reinterpret_cast<const short8*>(wa + s * 32);
    if (DUAL) {
      const ushort* wb = WB + (wave * 16 + rfrag) * 128 + kgrp * 8;
#pragma unroll
      for (int s = 0; s < 4; ++s) wfB[s] = *reinterpret_cast<const short8*>(wb + s * 32);
    }
  }
  __syncthreads();

  f32x4 acc[4];
#pragma unroll
  for (int i = 0; i < 4; ++i) acc[i] = (f32x4){0.f, 0.f, 0.f, 0.f};

  const int rs = (rfrag & 7) << 4;
#pragma unroll
  for (int strip = 0; strip < 4; ++strip) {
    const int r = strip * 16 + rfrag;
    short8 af[4];
#pragma unroll
    for (int s = 0; s < 4; ++s)
      af[s] = *reinterpret_cast<const short8*>((const char*)sA + r * 256 + ((kgrp * 16 + s * 64) ^ rs));
#pragma unroll
    for (int s = 0; s < 4; ++s)
      acc[strip] = __builtin_amdgcn_mfma_f32_16x16x32_bf16(af[s], wfA[s], acc[strip], 0, 0, 0);
    if (DUAL) {
      short8 bf[4];
#pragma unroll
      for (int s = 0; s < 4; ++s)
        bf[s] = *reinterpret_cast<const short8*>((const char*)sB + r * 256 + ((kgrp * 16 + s * 64) ^ rs));
#pragma unroll
      for (int s = 0; s < 4; ++s)
        acc[strip] = __builtin_amdgcn_mfma_f32_16x16x32_bf16(bf[s], wfB[s], acc[strip], 0, 0, 0);
    }
  }

  // BN partials (pre-rounding fp32), per-wave-owned columns -> direct global
  if (DUAL) {
    float s1 = 0.f, s2 = 0.f;
#pragma unroll
    for (int strip = 0; strip < 4; ++strip) {
#pragma unroll
      for (int rr = 0; rr < 4; ++rr) {
        int grow = row0 + strip * 16 + kgrp * 4 + rr;
        if (grow < M) {
          float v = acc[strip][rr];
          s1 += v;
          s2 = fmaf(v, v, s2);
        }
      }
    }
    s1 += __shfl_xor(s1, 16); s2 += __shfl_xor(s2, 16);
    s1 += __shfl_xor(s1, 32); s2 += __shfl_xor(s2, 32);
    if (kgrp == 0) {
      partial[(size_t)blockIdx.x * 256 + wave * 16 + rfrag] = s1;
      partial[(size_t)blockIdx.x * 256 + 128 + wave * 16 + rfrag] = s2;
    }
  }

  // repack into swizzled sZ
  const int cb = (wave * 16 + rfrag) * 2;
#pragma unroll
  for (int strip = 0; strip < 4; ++strip) {
#pragma unroll
    for (int rr = 0; rr < 4; ++rr) {
      int row = strip * 16 + kgrp * 4 + rr;
      *reinterpret_cast<ushort*>((char*)sZ + row * 256 + (cb ^ ((row & 7) << 4))) = f2bf(acc[strip][rr]);
    }
  }
  __syncthreads();

  // contiguous store (unswizzle on read)
#pragma unroll
  for (int i = 0; i < 2; ++i) {
    int lb = (wave * 2 + i) * 1024 + lane * 16;
    int row = lb >> 8, bin = lb & 255;
    int gr = row0 + row;
    if (gr < M) {
      uint4 v = *reinterpret_cast<const uint4*>((const char*)sZ + row * 256 + (bin ^ ((row & 7) << 4)));
      if (DUAL) {
        *reinterpret_cast<uint4*>((char*)Z + (size_t)gr * 256 + bin) = v;
      } else {
        if (bin < 128) *reinterpret_cast<uint4*>((char*)Z + (size_t)gr * 128 + bin) = v;
        else *reinterpret_cast<uint4*>((char*)Z2 + (size_t)gr * 128 + (bin - 128)) = v;
      }
    }
  }
}

// ---------------- BN reduce / finalize / apply ----------------

__global__ __launch_bounds__(256) void k_bn_reduce(const float* __restrict__ partial, int nblk,
                                                   float* __restrict__ stats) {
  float acc = 0.f;
  for (int b = blockIdx.x; b < nblk; b += gridDim.x) acc += partial[(size_t)b * 256 + threadIdx.x];
  atomicAdd(&stats[threadIdx.x], acc);
}

__global__ __launch_bounds__(128) void k_bn_finalize(const float* __restrict__ sums, const float* __restrict__ g,
                                                     const float* __restrict__ b, int M, float* __restrict__ ss) {
  int f = threadIdx.x;
  float inv = 1.0f / (float)M;
  float mean = sums[f] * inv;
  float var = sums[128 + f] * inv - mean * mean;
  var = fmaxf(var, 0.f);
  float sc = g[f] * rsqrtf(var + BN_EPS);
  ss[f] = sc;
  ss[128 + f] = fmaf(-mean, sc, b[f]);
}

__global__ __launch_bounds__(256) void k_bn_relu(uint2* __restrict__ Z, int n2, const float* __restrict__ ss) {
  for (int i = blockIdx.x * 256 + threadIdx.x; i < n2; i += gridDim.x * 256) {
    uint2 v = Z[i];
    int f0 = (i & 31) * 4;
    float4 sc = *reinterpret_cast<const float4*>(&ss[f0]);
    float4 sh = *reinterpret_cast<const float4*>(&ss[128 + f0]);
    float a0 = fmaxf(fmaf(bf2f_lo(v.x), sc.x, sh.x), 0.f);
    float a1 = fmaxf(fmaf(bf2f_hi(v.x), sc.y, sh.y), 0.f);
    float a2 = fmaxf(fmaf(bf2f_lo(v.y), sc.z, sh.z), 0.f);
    float a3 = fmaxf(fmaf(bf2f_hi(v.y), sc.w, sh.w), 0.f);
    v.x = (uint)f2bf(a0) | ((uint)f2bf(a1) << 16);
    v.y = (uint)f2bf(a2) | ((uint)f2bf(a3) << 16);
    Z[i] = v;
  }
}

// ---------------- layer-2 aggregation: out = mean(Y) + R + bias (fp32 out) ----------------
// Yb[N][64] (cols 0..C-1 used), Rb[N][64]; 8 nodes/wave, degree-sorted.

__global__ __launch_bounds__(256) void k_agg47(const ushort* __restrict__ Yb, const ushort* __restrict__ Rb,
                                               const float* __restrict__ bias, const int* __restrict__ rp,
                                               const int* __restrict__ csr, const float* __restrict__ deg_inv,
                                               const int* __restrict__ perm, float* __restrict__ out,
                                               int N, int C) {
  const int wave = threadIdx.x >> 6, lane = threadIdx.x & 63;
  const int sub = lane >> 3, li = lane & 7;
  const int gi = blockIdx.x * 32 + wave * 8 + sub;
  if (gi >= N) return;
  const int node = perm[gi];
  const int start = rp[node];
  const int c = rp[node + 1] - start;
  const uint4* Y16 = reinterpret_cast<const uint4*>(Yb);
  float a0 = 0.f, a1 = 0.f, a2 = 0.f, a3 = 0.f, a4 = 0.f, a5 = 0.f, a6 = 0.f, a7 = 0.f;
  int p = 0;
  for (; p + 7 < c; p += 8) {
    int idx[8];
#pragma unroll
    for (int u = 0; u < 8; ++u) idx[u] = csr[start + p + u];
    uint4 v[8];
#pragma unroll
    for (int u = 0; u < 8; ++u) v[u] = Y16[(size_t)idx[u] * 8 + li];
#pragma unroll
    for (int u = 0; u < 8; ++u) {
      a0 += bf2f_lo(v[u].x); a1 += bf2f_hi(v[u].x);
      a2 += bf2f_lo(v[u].y); a3 += bf2f_hi(v[u].y);
      a4 += bf2f_lo(v[u].z); a5 += bf2f_hi(v[u].z);
      a6 += bf2f_lo(v[u].w); a7 += bf2f_hi(v[u].w);
    }
  }
  for (; p < c; ++p) {
    uint4 v = Y16[(size_t)csr[start + p] * 8 + li];
    a0 += bf2f_lo(v.x); a1 += bf2f_hi(v.x);
    a2 += bf2f_lo(v.y); a3 += bf2f_hi(v.y);
    a4 += bf2f_lo(v.z); a5 += bf2f_hi(v.z);
    a6 += bf2f_lo(v.w); a7 += bf2f_hi(v.w);
  }
  const float di = deg_inv[node];
  uint4 sv = reinterpret_cast<const uint4*>(Rb)[(size_t)node * 8 + li];
  float s[8] = {bf2f_lo(sv.x), bf2f_hi(sv.x), bf2f_lo(sv.y), bf2f_hi(sv.y),
                bf2f_lo(sv.z), bf2f_hi(sv.z), bf2f_lo(sv.w), bf2f_hi(sv.w)};
  float a[8] = {a0, a1, a2, a3, a4, a5, a6, a7};
#pragma unroll
  for (int j = 0; j < 8; ++j) {
    int f = li * 8 + j;
    if (f < C) out[(size_t)node * C + f] = fmaf(a[j], di, s[j] + bias[f]);
  }
}

// ---------------- host launch ----------------

extern "C" void kernel_launch(void* const* d_in, const int* in_sizes, int n_in,
                              void* d_out, int out_size, void* d_ws, size_t ws_size,
                              hipStream_t stream) {
  const float* x   = (const float*)d_in[0];
  const int*   ei  = (const int*)d_in[1];
  const float* Wl0 = (const float*)d_in[2];
  const float* Wr0 = (const float*)d_in[4];
  const float* g0  = (const float*)d_in[5];
  const float* b0  = (const float*)d_in[6];
  const float* Wl1 = (const float*)d_in[7];
  const float* Wr1 = (const float*)d_in[9];
  const float* g1  = (const float*)d_in[10];
  const float* b1  = (const float*)d_in[11];
  const float* Wl2 = (const float*)d_in[12];
  const float* bl2 = (const float*)d_in[13];
  const float* Wr2 = (const float*)d_in[14];

  const int N = in_sizes[0] / 128;
  const int E = in_sizes[1] / 2;
  const int C = in_sizes[13];  // 47

  const int* edst = ei;
  const int* esrc = ei + E;

  char* w = (char*)d_ws;
  auto al = [](size_t v) { return (v + 255) & ~(size_t)255; };
  size_t off = 0;
  int*    bcnt    = (int*)(w + off);    off = al(off + NBUCKETS * 4);
  int*    brp     = (int*)(w + off);    off = al(off + (NBUCKETS + 1) * 4);
  int*    bcur    = (int*)(w + off);    off = al(off + NBUCKETS * 4);
  int*    dhist   = (int*)(w + off);    off = al(off + 64 * 4);
  int*    dcur    = (int*)(w + off);    off = al(off + 64 * 4);
  float*  stats   = (float*)(w + off);  off = al(off + 512 * 4);       // sums[256] + ss[256]
  int*    rp      = (int*)(w + off);    off = al(off + (size_t)(N + 1) * 4);
  float*  deg_inv = (float*)(w + off);  off = al(off + (size_t)N * 4);
  int*    perm    = (int*)(w + off);    off = al(off + (size_t)N * 4);
  int*    csr     = (int*)(w + off);    off = al(off + (size_t)E * 4);
  uint*   ebuf    = (uint*)(w + off);   off = al(off + (size_t)E * 4);
  ushort* Xb      = (ushort*)(w + off); off = al(off + (size_t)N * 128 * 2);
  ushort* hA      = (ushort*)(w + off); off = al(off + (size_t)N * 128 * 2);
  ushort* hB      = (ushort*)(w + off); off = al(off + (size_t)N * 128 * 2);
  ushort* W0l     = (ushort*)(w + off); off = al(off + 16384 * 2);
  ushort* W0r     = (ushort*)(w + off); off = al(off + 16384 * 2);
  ushort* W1l     = (ushort*)(w + off); off = al(off + 16384 * 2);
  ushort* W1r     = (ushort*)(w + off); off = al(off + 16384 * 2);
  ushort* Wc      = (ushort*)(w + off); off = al(off + 16384 * 2);
  const int nblkG = (N + 63) / 64;
  float*  partial = (float*)(w + off);  off = al(off + (size_t)nblkG * 256 * 4);

  ushort* Yb = hA;                       // [N][64] bf16
  ushort* Rb = hA + (size_t)N * 64;      // [N][64] bf16

  const int nbBuck = (N + 1023) / 1024;
  const int binGrid = (E + 8191) / 8192;
  const int degGrid = (N + 8191) / 8192;
  const int agg128Grid = (N + 15) / 16;
  const int agg47Grid = (N + 31) / 32;

  // casts + weight prep
  k_cast<<<2048, 256, 0, stream>>>(x, Xb, N * 32);
  k_prep_weights<<<128, 256, 0, stream>>>(Wl0, Wr0, Wl1, Wr1, Wl2, Wr2, W0l, W0r, W1l, W1r, Wc, C);

  // bucketed CSR build + degree-sorted permutation
  hipMemsetAsync(bcnt, 0, NBUCKETS * 4, stream);
  hipMemsetAsync(dhist, 0, 64 * 4, stream);
  k_bucket_hist<<<256, 256, 0, stream>>>(edst, E, bcnt);
  k_bucket_scan<<<1, 128, 0, stream>>>(bcnt, brp, bcur);
  k_binscatter<<<binGrid, 256, 0, stream>>>(edst, esrc, E, bcur, ebuf);
  k_bucket_build<<<nbBuck, 512, 0, stream>>>(ebuf, brp, rp, deg_inv, csr, dhist, N, E);
  k_deg_scan<<<1, 64, 0, stream>>>(dhist, dcur);
  k_deg_scatter<<<degGrid, 512, 0, stream>>>(rp, N, dcur, perm);

  // Layer 0
  k_agg128<<<agg128Grid, 256, 0, stream>>>(Xb, rp, csr, deg_inv, perm, hA, N);
  k_gemm<true><<<nblkG, 512, 0, stream>>>(hA, Xb, W0l, W0r, partial, hB, nullptr, N);
  hipMemsetAsync(stats, 0, 256 * 4, stream);
  k_bn_reduce<<<64, 256, 0, stream>>>(partial, nblkG, stats);
  k_bn_finalize<<<1, 128, 0, stream>>>(stats, g0, b0, N, stats + 256);
  k_bn_relu<<<2048, 256, 0, stream>>>((uint2*)hB, N * 32, stats + 256);

  // Layer 1 (in-place into hB: each block stages its own rows before storing them)
  k_agg128<<<agg128Grid, 256, 0, stream>>>(hB, rp, csr, deg_inv, perm, hA, N);
  k_gemm<true><<<nblkG, 512, 0, stream>>>(hA, hB, W1l, W1r, partial, hB, nullptr, N);
  hipMemsetAsync(stats, 0, 256 * 4, stream);
  k_bn_reduce<<<64, 256, 0, stream>>>(partial, nblkG, stats);
  k_bn_finalize<<<1, 128, 0, stream>>>(stats, g1, b1, N, stats + 256);
  k_bn_relu<<<2048, 256, 0, stream>>>((uint2*)hB, N * 32, stats + 256);

  // Layer 2: transform first (mean is linear), then aggregate in C-dim space
  k_gemm<false><<<nblkG, 512, 0, stream>>>(hB, nullptr, Wc, nullptr, nullptr, Yb, Rb, N);
  k_agg47<<<agg47Grid, 256, 0, stream>>>(Yb, Rb, bl2, rp, csr, deg_inv, perm, (float*)d_out, N, C);
}

// Round 8
// 314.077 us; speedup vs baseline: 1.1484x; 1.1484x over previous
//
#include <hip/hip_runtime.h>

typedef __attribute__((ext_vector_type(8))) short short8;
typedef __attribute__((ext_vector_type(4))) float f32x4;

constexpr float BN_EPS = 1e-5f;
#define NBUCKETS 128   // buckets of 1024 nodes; N <= 131072
#define SLOT 24576     // per-bucket edge slot; mean 16384/bucket @ E/N=16, +63 sigma headroom

__device__ __forceinline__ ushort f2bf(float f) {
  uint u = __float_as_uint(f);
  u = (u + 0x7fffu + ((u >> 16) & 1u)) >> 16;
  return (ushort)u;
}
__device__ __forceinline__ float bf2f(ushort h) { return __uint_as_float((uint)h << 16); }
__device__ __forceinline__ float bf2f_lo(uint v) { return __uint_as_float(v << 16); }
__device__ __forceinline__ float bf2f_hi(uint v) { return __uint_as_float(v & 0xffff0000u); }

typedef __attribute__((address_space(1))) const unsigned int* as1_cu32;
typedef __attribute__((address_space(3))) unsigned int* as3_u32;
__device__ __forceinline__ void gload_lds16(const void* g, void* l) {
  __builtin_amdgcn_global_load_lds((as1_cu32)g, (as3_u32)l, 16, 0, 0);
}

// ---------------- fp32 -> bf16 cast (x) ----------------

__global__ __launch_bounds__(256) void k_cast(const float* __restrict__ in, ushort* __restrict__ out, int n4) {
  for (int i = blockIdx.x * 256 + threadIdx.x; i < n4; i += gridDim.x * 256) {
    float4 v = reinterpret_cast<const float4*>(in)[i];
    ushort4 o;
    o.x = f2bf(v.x); o.y = f2bf(v.y); o.z = f2bf(v.z); o.w = f2bf(v.w);
    reinterpret_cast<ushort4*>(out)[i] = o;
  }
}

// blocks 0-63: cast 4 128x128 weights; blocks 64-127: packed layer-2 weight;
// block 128: init bcur (bucket slot bases) + zero both BN stats buffers.
__global__ __launch_bounds__(256) void k_prep_init(const float* __restrict__ Wl0, const float* __restrict__ Wr0,
                                                   const float* __restrict__ Wl1, const float* __restrict__ Wr1,
                                                   const float* __restrict__ Wl2, const float* __restrict__ Wr2,
                                                   ushort* __restrict__ W0l, ushort* __restrict__ W0r,
                                                   ushort* __restrict__ W1l, ushort* __restrict__ W1r,
                                                   ushort* __restrict__ Wc, int* __restrict__ bcur,
                                                   float* __restrict__ statsAll, int C) {
  int b = blockIdx.x;
  if (b < 64) {
    const float* src = (b < 16) ? Wl0 : (b < 32) ? Wr0 : (b < 48) ? Wl1 : Wr1;
    ushort* dst = (b < 16) ? W0l : (b < 32) ? W0r : (b < 48) ? W1l : W1r;
    int i = (b & 15) * 256 + threadIdx.x;
    float4 v = reinterpret_cast<const float4*>(src)[i];
    ushort4 o;
    o.x = f2bf(v.x); o.y = f2bf(v.y); o.z = f2bf(v.z); o.w = f2bf(v.w);
    reinterpret_cast<ushort4*>(dst)[i] = o;
  } else if (b < 128) {
    int i = (b - 64) * 256 + threadIdx.x;  // 16384
    int r = i >> 7, k = i & 127;
    float v = 0.f;
    if (r < C) v = Wl2[r * 128 + k];
    else if (r >= 64 && r < 64 + C) v = Wr2[(r - 64) * 128 + k];
    Wc[i] = f2bf(v);
  } else {
    if (threadIdx.x < NBUCKETS) bcur[threadIdx.x] = threadIdx.x * SLOT;
    for (int i = threadIdx.x; i < 512; i += 256) statsAll[i] = 0.f;
  }
}

// ---------------- single-pass bucket binning: (dst & 1023) | (src << 10) ----------------

__global__ __launch_bounds__(256) void k_binscatter(const int* __restrict__ dst, const int* __restrict__ src, int E,
                                                    int* __restrict__ bcur, uint* __restrict__ ebuf) {
  __shared__ int h[NBUCKETS];
  __shared__ int base[NBUCKETS];
  __shared__ int cur[NBUCKETS];
  const int e0 = blockIdx.x * 8192;
  const int e1 = min(e0 + 8192, E);
  for (int i = threadIdx.x; i < NBUCKETS; i += 256) h[i] = 0;
  __syncthreads();
  for (int e = e0 + threadIdx.x * 4; e < e1; e += 1024) {
    int4 d = *reinterpret_cast<const int4*>(&dst[e]);
    if (e + 3 < e1) {
      atomicAdd(&h[d.x >> 10], 1); atomicAdd(&h[d.y >> 10], 1);
      atomicAdd(&h[d.z >> 10], 1); atomicAdd(&h[d.w >> 10], 1);
    } else {
      for (int j = 0; e + j < e1; ++j) atomicAdd(&h[dst[e + j] >> 10], 1);
    }
  }
  __syncthreads();
  if (threadIdx.x < NBUCKETS) {
    base[threadIdx.x] = atomicAdd(&bcur[threadIdx.x], h[threadIdx.x]);
    cur[threadIdx.x] = 0;
  }
  __syncthreads();
  for (int e = e0 + threadIdx.x * 4; e < e1; e += 1024) {
    int4 d = *reinterpret_cast<const int4*>(&dst[e]);
    int4 s = *reinterpret_cast<const int4*>(&src[e]);
    int dd[4] = {d.x, d.y, d.z, d.w};
    int ss[4] = {s.x, s.y, s.z, s.w};
    for (int j = 0; j < 4 && e + j < e1; ++j) {
      int b = dd[j] >> 10;
      int pos = base[b] + atomicAdd(&cur[b], 1);
      ebuf[pos] = (uint)(dd[j] & 1023) | ((uint)ss[j] << 10);
    }
  }
}

// per-bucket: node counts, LDS scan, rp/deg/deg_inv, scatter src into csr
__global__ __launch_bounds__(512) void k_bucket_build(const uint* __restrict__ ebuf, const int* __restrict__ bend,
                                                      int* __restrict__ rp, int* __restrict__ deg,
                                                      float* __restrict__ deg_inv, int* __restrict__ csr, int N) {
  __shared__ int cnt[1024];
  __shared__ int pre[1024];
  __shared__ int tmp[1024];
  const int blk = blockIdx.x, tid = threadIdx.x;
  const int base = blk << 10;
  const int p0 = blk * SLOT, p1 = bend[blk];
  for (int i = tid; i < 1024; i += 512) cnt[i] = 0;
  __syncthreads();
  for (int p = p0 + tid; p < p1; p += 512) atomicAdd(&cnt[ebuf[p] & 1023u], 1);
  __syncthreads();
  for (int i = tid; i < 1024; i += 512) pre[i] = cnt[i];
  __syncthreads();
  for (int off = 1; off < 1024; off <<= 1) {
    for (int i = tid; i < 1024; i += 512) tmp[i] = (i >= off) ? pre[i - off] : 0;
    __syncthreads();
    for (int i = tid; i < 1024; i += 512) pre[i] += tmp[i];
    __syncthreads();
  }
  for (int i = tid; i < 1024; i += 512) {
    int node = base + i;
    if (node < N) {
      int c = cnt[i];
      rp[node] = p0 + pre[i] - c;
      deg[node] = c;
      deg_inv[node] = 1.0f / (float)max(c, 1);
    }
    tmp[i] = pre[i] - cnt[i];  // scatter cursor
  }
  __syncthreads();
  for (int p = p0 + tid; p < p1; p += 512) {
    uint pr = ebuf[p];
    int pos = p0 + atomicAdd(&tmp[pr & 1023u], 1);
    csr[pos] = (int)(pr >> 10);
  }
}

// ---------------- fused mean-agg + dual MFMA GEMM ----------------
// Block = 64 nodes, 512 threads (8 waves). Phase 1: issue B-tile global_load_lds
// (pre-swizzled source), gather-mean the block's 64 node rows and ds_write them
// as the swizzled LDS A-tile. Phase 2: wave w computes output cols [16w,16w+16)
// with strip weights in registers; BN partials from pre-rounded fp32; Z repacked
// through LDS (reusing sA) for contiguous dwordx4 stores.

__global__ __launch_bounds__(512, 4) void k_fused(const ushort* __restrict__ X, const ushort* __restrict__ Bsrc,
                                                  const ushort* __restrict__ WA, const ushort* __restrict__ WB,
                                                  const int* __restrict__ rp, const int* __restrict__ deg,
                                                  const float* __restrict__ deg_inv, const int* __restrict__ csr,
                                                  float* __restrict__ partial, ushort* __restrict__ Z, int M) {
  __shared__ ushort sA[64 * 128];
  __shared__ ushort sB[64 * 128];
  const int tid = threadIdx.x;
  const int wave = tid >> 6, lane = tid & 63;
  const int rfrag = lane & 15, kgrp = lane >> 4;
  const int li = rfrag;  // 16B column within a 256B row
  const int row0 = blockIdx.x * 64;

  // B-tile staging (in flight across the whole agg phase)
#pragma unroll
  for (int i = 0; i < 2; ++i) {
    int c = wave * 2 + i;
    int lb = c * 1024 + lane * 16;
    int row = lb >> 8, bin = lb & 255;
    int gr = min(row0 + row, M - 1);
    int sb = bin ^ ((row & 7) << 4);
    gload_lds16((const char*)Bsrc + (size_t)gr * 256 + sb, (char*)sB + c * 1024);
  }

  // agg phase: wave handles 8 nodes (2 groups of 4 via sub = kgrp)
  const uint4* X16 = reinterpret_cast<const uint4*>(X);
#pragma unroll
  for (int g = 0; g < 2; ++g) {
    const int lrow = wave * 8 + g * 4 + kgrp;
    const int node = row0 + lrow;
    float a0 = 0.f, a1 = 0.f, a2 = 0.f, a3 = 0.f, a4 = 0.f, a5 = 0.f, a6 = 0.f, a7 = 0.f;
    if (node < M) {
      const int start = rp[node];
      const int c = deg[node];
      int p = 0;
      for (; p + 7 < c; p += 8) {
        int idx[8];
#pragma unroll
        for (int u = 0; u < 8; ++u) idx[u] = csr[start + p + u];
        uint4 v[8];
#pragma unroll
        for (int u = 0; u < 8; ++u) v[u] = X16[(size_t)idx[u] * 16 + li];
#pragma unroll
        for (int u = 0; u < 8; ++u) {
          a0 += bf2f_lo(v[u].x); a1 += bf2f_hi(v[u].x);
          a2 += bf2f_lo(v[u].y); a3 += bf2f_hi(v[u].y);
          a4 += bf2f_lo(v[u].z); a5 += bf2f_hi(v[u].z);
          a6 += bf2f_lo(v[u].w); a7 += bf2f_hi(v[u].w);
        }
      }
      if (p + 3 < c) {
        int idx[4];
#pragma unroll
        for (int u = 0; u < 4; ++u) idx[u] = csr[start + p + u];
        uint4 v[4];
#pragma unroll
        for (int u = 0; u < 4; ++u) v[u] = X16[(size_t)idx[u] * 16 + li];
#pragma unroll
        for (int u = 0; u < 4; ++u) {
          a0 += bf2f_lo(v[u].x); a1 += bf2f_hi(v[u].x);
          a2 += bf2f_lo(v[u].y); a3 += bf2f_hi(v[u].y);
          a4 += bf2f_lo(v[u].z); a5 += bf2f_hi(v[u].z);
          a6 += bf2f_lo(v[u].w); a7 += bf2f_hi(v[u].w);
        }
        p += 4;
      }
      for (; p < c; ++p) {
        uint4 v = X16[(size_t)csr[start + p] * 16 + li];
        a0 += bf2f_lo(v.x); a1 += bf2f_hi(v.x);
        a2 += bf2f_lo(v.y); a3 += bf2f_hi(v.y);
        a4 += bf2f_lo(v.z); a5 += bf2f_hi(v.z);
        a6 += bf2f_lo(v.w); a7 += bf2f_hi(v.w);
      }
      const float di = deg_inv[node];
      a0 *= di; a1 *= di; a2 *= di; a3 *= di;
      a4 *= di; a5 *= di; a6 *= di; a7 *= di;
    }
    uint4 o;
    o.x = (uint)f2bf(a0) | ((uint)f2bf(a1) << 16);
    o.y = (uint)f2bf(a2) | ((uint)f2bf(a3) << 16);
    o.z = (uint)f2bf(a4) | ((uint)f2bf(a5) << 16);
    o.w = (uint)f2bf(a6) | ((uint)f2bf(a7) << 16);
    *reinterpret_cast<uint4*>((char*)sA + lrow * 256 + ((li * 16) ^ ((lrow & 7) << 4))) = o;
  }

  // weight fragments for this wave's column strip (L2-hot; in flight over barrier)
  short8 wfA[4], wfB[4];
  {
    const ushort* wa = WA + (wave * 16 + rfrag) * 128 + kgrp * 8;
    const ushort* wb = WB + (wave * 16 + rfrag) * 128 + kgrp * 8;
#pragma unroll
    for (int s = 0; s < 4; ++s) {
      wfA[s] = *reinterpret_cast<const short8*>(wa + s * 32);
      wfB[s] = *reinterpret_cast<const short8*>(wb + s * 32);
    }
  }
  __syncthreads();  // A-tile ds_writes visible; B-tile gload_lds drained

  f32x4 acc[4];
#pragma unroll
  for (int i = 0; i < 4; ++i) acc[i] = (f32x4){0.f, 0.f, 0.f, 0.f};

  const int rs = (rfrag & 7) << 4;
#pragma unroll
  for (int strip = 0; strip < 4; ++strip) {
    const int r = strip * 16 + rfrag;
    short8 af[4], bf[4];
#pragma unroll
    for (int s = 0; s < 4; ++s) {
      int off = (kgrp * 16 + s * 64) ^ rs;
      af[s] = *reinterpret_cast<const short8*>((const char*)sA + r * 256 + off);
      bf[s] = *reinterpret_cast<const short8*>((const char*)sB + r * 256 + off);
    }
#pragma unroll
    for (int s = 0; s < 4; ++s)
      acc[strip] = __builtin_amdgcn_mfma_f32_16x16x32_bf16(af[s], wfA[s], acc[strip], 0, 0, 0);
#pragma unroll
    for (int s = 0; s < 4; ++s)
      acc[strip] = __builtin_amdgcn_mfma_f32_16x16x32_bf16(bf[s], wfB[s], acc[strip], 0, 0, 0);
  }

  // BN partials (pre-rounding fp32), per-wave-owned columns -> direct global
  {
    float s1 = 0.f, s2 = 0.f;
#pragma unroll
    for (int strip = 0; strip < 4; ++strip) {
#pragma unroll
      for (int rr = 0; rr < 4; ++rr) {
        int grow = row0 + strip * 16 + kgrp * 4 + rr;
        if (grow < M) {
          float v = acc[strip][rr];
          s1 += v;
          s2 = fmaf(v, v, s2);
        }
      }
    }
    s1 += __shfl_xor(s1, 16); s2 += __shfl_xor(s2, 16);
    s1 += __shfl_xor(s1, 32); s2 += __shfl_xor(s2, 32);
    if (kgrp == 0) {
      partial[(size_t)blockIdx.x * 256 + wave * 16 + rfrag] = s1;
      partial[(size_t)blockIdx.x * 256 + 128 + wave * 16 + rfrag] = s2;
    }
  }
  __syncthreads();  // all sA/sB fragment reads done before repack

  // repack into swizzled sA (reused as Z-tile)
  const int cb = (wave * 16 + rfrag) * 2;
#pragma unroll
  for (int strip = 0; strip < 4; ++strip) {
#pragma unroll
    for (int rr = 0; rr < 4; ++rr) {
      int row = strip * 16 + kgrp * 4 + rr;
      *reinterpret_cast<ushort*>((char*)sA + row * 256 + (cb ^ ((row & 7) << 4))) = f2bf(acc[strip][rr]);
    }
  }
  __syncthreads();

  // contiguous Z store (unswizzle on read)
#pragma unroll
  for (int i = 0; i < 2; ++i) {
    int lb = (wave * 2 + i) * 1024 + lane * 16;
    int row = lb >> 8, bin = lb & 255;
    int gr = row0 + row;
    if (gr < M)
      *reinterpret_cast<uint4*>((char*)Z + (size_t)gr * 256 + bin) =
          *reinterpret_cast<const uint4*>((const char*)sA + row * 256 + (bin ^ ((row & 7) << 4)));
  }
}

// ---------------- layer-2 MFMA GEMM: Yb/Rb = H @ Wc^T split ----------------

__global__ __launch_bounds__(512, 6) void k_gemm1(const ushort* __restrict__ H, const ushort* __restrict__ Wc,
                                                  ushort* __restrict__ Yb, ushort* __restrict__ Rb, int M) {
  __shared__ ushort sA[64 * 128];
  const int tid = threadIdx.x;
  const int wave = tid >> 6, lane = tid & 63;
  const int rfrag = lane & 15, kgrp = lane >> 4;
  const int row0 = blockIdx.x * 64;

#pragma unroll
  for (int i = 0; i < 2; ++i) {
    int c = wave * 2 + i;
    int lb = c * 1024 + lane * 16;
    int row = lb >> 8, bin = lb & 255;
    int gr = min(row0 + row, M - 1);
    int sb = bin ^ ((row & 7) << 4);
    gload_lds16((const char*)H + (size_t)gr * 256 + sb, (char*)sA + c * 1024);
  }

  short8 wf[4];
  {
    const ushort* wp = Wc + (wave * 16 + rfrag) * 128 + kgrp * 8;
#pragma unroll
    for (int s = 0; s < 4; ++s) wf[s] = *reinterpret_cast<const short8*>(wp + s * 32);
  }
  __syncthreads();

  f32x4 acc[4];
#pragma unroll
  for (int i = 0; i < 4; ++i) acc[i] = (f32x4){0.f, 0.f, 0.f, 0.f};
  const int rs = (rfrag & 7) << 4;
#pragma unroll
  for (int strip = 0; strip < 4; ++strip) {
    const int r = strip * 16 + rfrag;
    short8 af[4];
#pragma unroll
    for (int s = 0; s < 4; ++s)
      af[s] = *reinterpret_cast<const short8*>((const char*)sA + r * 256 + ((kgrp * 16 + s * 64) ^ rs));
#pragma unroll
    for (int s = 0; s < 4; ++s)
      acc[strip] = __builtin_amdgcn_mfma_f32_16x16x32_bf16(af[s], wf[s], acc[strip], 0, 0, 0);
  }
  __syncthreads();

  const int cb = (wave * 16 + rfrag) * 2;
#pragma unroll
  for (int strip = 0; strip < 4; ++strip) {
#pragma unroll
    for (int rr = 0; rr < 4; ++rr) {
      int row = strip * 16 + kgrp * 4 + rr;
      *reinterpret_cast<ushort*>((char*)sA + row * 256 + (cb ^ ((row & 7) << 4))) = f2bf(acc[strip][rr]);
    }
  }
  __syncthreads();

#pragma unroll
  for (int i = 0; i < 2; ++i) {
    int lb = (wave * 2 + i) * 1024 + lane * 16;
    int row = lb >> 8, bin = lb & 255;
    int gr = row0 + row;
    if (gr < M) {
      uint4 v = *reinterpret_cast<const uint4*>((const char*)sA + row * 256 + (bin ^ ((row & 7) << 4)));
      if (bin < 128) *reinterpret_cast<uint4*>((char*)Yb + (size_t)gr * 128 + bin) = v;
      else *reinterpret_cast<uint4*>((char*)Rb + (size_t)gr * 128 + (bin - 128)) = v;
    }
  }
}

// ---------------- BN reduce / fused finalize+apply ----------------

__global__ __launch_bounds__(256) void k_bn_reduce(const float* __restrict__ partial, int nblk,
                                                   float* __restrict__ stats) {
  float acc = 0.f;
  for (int b = blockIdx.x; b < nblk; b += gridDim.x) acc += partial[(size_t)b * 256 + threadIdx.x];
  atomicAdd(&stats[threadIdx.x], acc);
}

__global__ __launch_bounds__(256) void k_bn_relu(uint2* __restrict__ Z, int n2, const float* __restrict__ sums,
                                                 const float* __restrict__ g, const float* __restrict__ b,
                                                 float invM) {
  __shared__ float ss[256];
  if (threadIdx.x < 128) {
    int f = threadIdx.x;
    float mean = sums[f] * invM;
    float var = fmaxf(sums[128 + f] * invM - mean * mean, 0.f);
    float sc = g[f] * rsqrtf(var + BN_EPS);
    ss[f] = sc;
    ss[128 + f] = fmaf(-mean, sc, b[f]);
  }
  __syncthreads();
  for (int i = blockIdx.x * 256 + threadIdx.x; i < n2; i += gridDim.x * 256) {
    uint2 v = Z[i];
    int f0 = (i & 31) * 4;
    float a0 = fmaxf(fmaf(bf2f_lo(v.x), ss[f0 + 0], ss[128 + f0 + 0]), 0.f);
    float a1 = fmaxf(fmaf(bf2f_hi(v.x), ss[f0 + 1], ss[128 + f0 + 1]), 0.f);
    float a2 = fmaxf(fmaf(bf2f_lo(v.y), ss[f0 + 2], ss[128 + f0 + 2]), 0.f);
    float a3 = fmaxf(fmaf(bf2f_hi(v.y), ss[f0 + 3], ss[128 + f0 + 3]), 0.f);
    v.x = (uint)f2bf(a0) | ((uint)f2bf(a1) << 16);
    v.y = (uint)f2bf(a2) | ((uint)f2bf(a3) << 16);
    Z[i] = v;
  }
}

// ---------------- layer-2 aggregation: out = mean(Y) + R + bias (fp32 out) ----------------

__global__ __launch_bounds__(256) void k_agg47(const ushort* __restrict__ Yb, const ushort* __restrict__ Rb,
                                               const float* __restrict__ bias, const int* __restrict__ rp,
                                               const int* __restrict__ deg, const float* __restrict__ deg_inv,
                                               const int* __restrict__ csr, float* __restrict__ out,
                                               int N, int C) {
  const int wave = threadIdx.x >> 6, lane = threadIdx.x & 63;
  const int sub = lane >> 3, li = lane & 7;
  const int node = blockIdx.x * 32 + wave * 8 + sub;
  if (node >= N) return;
  const int start = rp[node];
  const int c = deg[node];
  const uint4* Y16 = reinterpret_cast<const uint4*>(Yb);
  float a0 = 0.f, a1 = 0.f, a2 = 0.f, a3 = 0.f, a4 = 0.f, a5 = 0.f, a6 = 0.f, a7 = 0.f;
  int p = 0;
  for (; p + 7 < c; p += 8) {
    int idx[8];
#pragma unroll
    for (int u = 0; u < 8; ++u) idx[u] = csr[start + p + u];
    uint4 v[8];
#pragma unroll
    for (int u = 0; u < 8; ++u) v[u] = Y16[(size_t)idx[u] * 8 + li];
#pragma unroll
    for (int u = 0; u < 8; ++u) {
      a0 += bf2f_lo(v[u].x); a1 += bf2f_hi(v[u].x);
      a2 += bf2f_lo(v[u].y); a3 += bf2f_hi(v[u].y);
      a4 += bf2f_lo(v[u].z); a5 += bf2f_hi(v[u].z);
      a6 += bf2f_lo(v[u].w); a7 += bf2f_hi(v[u].w);
    }
  }
  for (; p < c; ++p) {
    uint4 v = Y16[(size_t)csr[start + p] * 8 + li];
    a0 += bf2f_lo(v.x); a1 += bf2f_hi(v.x);
    a2 += bf2f_lo(v.y); a3 += bf2f_hi(v.y);
    a4 += bf2f_lo(v.z); a5 += bf2f_hi(v.z);
    a6 += bf2f_lo(v.w); a7 += bf2f_hi(v.w);
  }
  const float di = deg_inv[node];
  uint4 sv = reinterpret_cast<const uint4*>(Rb)[(size_t)node * 8 + li];
  float s[8] = {bf2f_lo(sv.x), bf2f_hi(sv.x), bf2f_lo(sv.y), bf2f_hi(sv.y),
                bf2f_lo(sv.z), bf2f_hi(sv.z), bf2f_lo(sv.w), bf2f_hi(sv.w)};
  float a[8] = {a0, a1, a2, a3, a4, a5, a6, a7};
#pragma unroll
  for (int j = 0; j < 8; ++j) {
    int f = li * 8 + j;
    if (f < C) out[(size_t)node * C + f] = fmaf(a[j], di, s[j] + bias[f]);
  }
}

// ---------------- host launch ----------------

extern "C" void kernel_launch(void* const* d_in, const int* in_sizes, int n_in,
                              void* d_out, int out_size, void* d_ws, size_t ws_size,
                              hipStream_t stream) {
  const float* x   = (const float*)d_in[0];
  const int*   ei  = (const int*)d_in[1];
  const float* Wl0 = (const float*)d_in[2];
  const float* Wr0 = (const float*)d_in[4];
  const float* g0  = (const float*)d_in[5];
  const float* b0  = (const float*)d_in[6];
  const float* Wl1 = (const float*)d_in[7];
  const float* Wr1 = (const float*)d_in[9];
  const float* g1  = (const float*)d_in[10];
  const float* b1  = (const float*)d_in[11];
  const float* Wl2 = (const float*)d_in[12];
  const float* bl2 = (const float*)d_in[13];
  const float* Wr2 = (const float*)d_in[14];

  const int N = in_sizes[0] / 128;
  const int E = in_sizes[1] / 2;
  const int C = in_sizes[13];  // 47

  const int* edst = ei;
  const int* esrc = ei + E;

  char* w = (char*)d_ws;
  auto al = [](size_t v) { return (v + 255) & ~(size_t)255; };
  size_t off = 0;
  int*    bcur    = (int*)(w + off);    off = al(off + NBUCKETS * 4);
  float*  stats   = (float*)(w + off);  off = al(off + 512 * 4);   // stats0[256] + stats1[256]
  int*    rp      = (int*)(w + off);    off = al(off + (size_t)N * 4);
  int*    deg     = (int*)(w + off);    off = al(off + (size_t)N * 4);
  float*  deg_inv = (float*)(w + off);  off = al(off + (size_t)N * 4);
  int*    csr     = (int*)(w + off);    off = al(off + (size_t)NBUCKETS * SLOT * 4);
  uint*   ebuf    = (uint*)(w + off);   off = al(off + (size_t)NBUCKETS * SLOT * 4);
  ushort* Xb      = (ushort*)(w + off); off = al(off + (size_t)N * 128 * 2);
  ushort* hA      = (ushort*)(w + off); off = al(off + (size_t)N * 128 * 2);
  ushort* hB      = (ushort*)(w + off); off = al(off + (size_t)N * 128 * 2);
  ushort* W0l     = (ushort*)(w + off); off = al(off + 16384 * 2);
  ushort* W0r     = (ushort*)(w + off); off = al(off + 16384 * 2);
  ushort* W1l     = (ushort*)(w + off); off = al(off + 16384 * 2);
  ushort* W1r     = (ushort*)(w + off); off = al(off + 16384 * 2);
  ushort* Wc      = (ushort*)(w + off); off = al(off + 16384 * 2);
  const int nblkG = (N + 63) / 64;
  float*  partial = (float*)(w + off);  off = al(off + (size_t)nblkG * 256 * 4);

  float* stats0 = stats;
  float* stats1 = stats + 256;
  ushort* Yb = hB;                    // layer-2 output reuses hB
  ushort* Rb = hB + (size_t)N * 64;

  const int binGrid = (E + 8191) / 8192;
  const int nbBuck = (N + 1023) / 1024;
  const int agg47Grid = (N + 31) / 32;
  const float invM = 1.0f / (float)N;

  // prep: cast x, weights, init bucket cursors + stats
  k_cast<<<2048, 256, 0, stream>>>(x, Xb, N * 32);
  k_prep_init<<<129, 256, 0, stream>>>(Wl0, Wr0, Wl1, Wr1, Wl2, Wr2, W0l, W0r, W1l, W1r, Wc,
                                       bcur, stats, C);

  // CSR build (single-pass binning)
  k_binscatter<<<binGrid, 256, 0, stream>>>(edst, esrc, E, bcur, ebuf);
  k_bucket_build<<<nbBuck, 512, 0, stream>>>(ebuf, bcur, rp, deg, deg_inv, csr, N);

  // Layer 0: fused agg+GEMM (gathers Xb, self term Xb) -> hB
  k_fused<<<nblkG, 512, 0, stream>>>(Xb, Xb, W0l, W0r, rp, deg, deg_inv, csr, partial, hB, N);
  k_bn_reduce<<<64, 256, 0, stream>>>(partial, nblkG, stats0);
  k_bn_relu<<<2048, 256, 0, stream>>>((uint2*)hB, N * 32, stats0, g0, b0, invM);

  // Layer 1: fused agg+GEMM (gathers hB, self term hB) -> hA
  k_fused<<<nblkG, 512, 0, stream>>>(hB, hB, W1l, W1r, rp, deg, deg_inv, csr, partial, hA, N);
  k_bn_reduce<<<64, 256, 0, stream>>>(partial, nblkG, stats1);
  k_bn_relu<<<2048, 256, 0, stream>>>((uint2*)hA, N * 32, stats1, g1, b1, invM);

  // Layer 2: transform (split Yb/Rb), then aggregate in C-dim space
  k_gemm1<<<nblkG, 512, 0, stream>>>(hA, Wc, Yb, Rb, N);
  k_agg47<<<agg47Grid, 256, 0, stream>>>(Yb, Rb, bl2, rp, deg, deg_inv, csr, (float*)d_out, N, C);
}